// Round 1
// baseline (299.914 us; speedup 1.0000x reference)
//
#include <hip/hip_runtime.h>
#include <hip/hip_bf16.h>

#define NP 512   // particles
#define DD 128   // dims

// ---------------------------------------------------------------------------
// Kernel 1: per-dimension exact median of upper-triangular pairwise squared
// differences via 4-pass radix select on float bits, then inv_bandwidth.
// One block per dimension d. 512 threads.
// ---------------------------------------------------------------------------
__global__ void __launch_bounds__(512)
median_bw_kernel(const float* __restrict__ particles, float* __restrict__ inv_bw)
{
    const int d = blockIdx.x;              // 0..127
    __shared__ float vals[NP];
    __shared__ int   hist[256];
    __shared__ int   sel_bin;
    __shared__ int   sel_sub;

    for (int i = threadIdx.x; i < NP; i += blockDim.x)
        vals[i] = particles[i * DD + d];
    __syncthreads();

    // m = N*(N-1)/2 = 130816 ; k = (m-1)//2 = 65407 (0-based lower median)
    int want = (NP * (NP - 1) / 2 - 1) / 2;
    unsigned prefix = 0u;

    for (int pass = 0; pass < 4; ++pass) {
        const int shift = 24 - 8 * pass;
        for (int b = threadIdx.x; b < 256; b += blockDim.x) hist[b] = 0;
        __syncthreads();

        for (int t = threadIdx.x; t < NP * NP; t += blockDim.x) {
            const int i = t >> 9;       // / 512
            const int j = t & (NP - 1); // % 512
            if (j > i) {
                const float df = vals[j] - vals[i];
                const unsigned key = __float_as_uint(df * df);
                // keys already matched on all bits above this byte?
                if (pass == 0 || (key >> (shift + 8)) == (prefix >> (shift + 8))) {
                    atomicAdd(&hist[(key >> shift) & 255], 1);
                }
            }
        }
        __syncthreads();

        if (threadIdx.x == 0) {
            int cum = 0, b = 0;
            for (; b < 255; ++b) {
                const int c = hist[b];
                if (cum + c > want) break;
                cum += c;
            }
            sel_bin = b;
            sel_sub = want - cum;
        }
        __syncthreads();
        prefix |= ((unsigned)sel_bin) << shift;
        want = sel_sub;
        __syncthreads();
    }

    if (threadIdx.x == 0) {
        const float median = __uint_as_float(prefix);
        const float h  = median / logf((float)(NP + 1));
        const float bw = fmaxf(h, 1e-9f);
        inv_bw[d] = 1.0f / bw;
    }
}

// ---------------------------------------------------------------------------
// Kernel 2: write log_kernel and grad_log_kernel, float4-vectorized.
// Flat float4 index t over (i, j, d4):  d4 = t & 31, j = (t>>5)&511, i = t>>14
// ---------------------------------------------------------------------------
__global__ void __launch_bounds__(256)
stein_out_kernel(const float* __restrict__ particles,
                 const float* __restrict__ inv_bw,
                 float4* __restrict__ out_lk,
                 float4* __restrict__ out_g)
{
    const float4* __restrict__ p4  = (const float4*)particles;
    const float4* __restrict__ ib4 = (const float4*)inv_bw;
    const int total = NP * NP * (DD / 4);   // 8,388,608

    for (int t = blockIdx.x * blockDim.x + threadIdx.x; t < total;
         t += gridDim.x * blockDim.x) {
        const int d4 = t & (DD / 4 - 1);        // 0..31
        const int j  = (t >> 5) & (NP - 1);     // 0..511
        const int i  = t >> 14;                 // 0..511

        const float4 xj = p4[j * (DD / 4) + d4];
        const float4 xi = p4[i * (DD / 4) + d4];
        const float4 ib = ib4[d4];

        float4 lk, g;
        {
            const float dx = xj.x - xi.x;
            lk.x = -(dx * dx * ib.x);
            g.x  = -2.0f * dx * ib.x;
        }
        {
            const float dx = xj.y - xi.y;
            lk.y = -(dx * dx * ib.y);
            g.y  = -2.0f * dx * ib.y;
        }
        {
            const float dx = xj.z - xi.z;
            lk.z = -(dx * dx * ib.z);
            g.z  = -2.0f * dx * ib.z;
        }
        {
            const float dx = xj.w - xi.w;
            lk.w = -(dx * dx * ib.w);
            g.w  = -2.0f * dx * ib.w;
        }
        out_lk[t] = lk;
        out_g[t]  = g;
    }
}

extern "C" void kernel_launch(void* const* d_in, const int* in_sizes, int n_in,
                              void* d_out, int out_size, void* d_ws, size_t ws_size,
                              hipStream_t stream)
{
    const float* particles = (const float*)d_in[0];
    float* out    = (float*)d_out;
    float* inv_bw = (float*)d_ws;   // 128 floats of scratch

    median_bw_kernel<<<DD, 512, 0, stream>>>(particles, inv_bw);

    float4* out_lk = (float4*)out;
    float4* out_g  = (float4*)(out + (size_t)NP * NP * DD);
    stein_out_kernel<<<2048, 256, 0, stream>>>(particles, inv_bw, out_lk, out_g);
}

// Round 2
// 83.459 us; speedup vs baseline: 3.5935x; 3.5935x over previous
//
#include <hip/hip_runtime.h>
#include <hip/hip_bf16.h>

#define NP 512   // particles
#define DD 128   // dims

// ---------------------------------------------------------------------------
// Kernel 1: per-dimension exact median of upper-triangular pairwise squared
// differences. One block (512 threads) per dimension d.
//   1) bitonic sort the 512 per-dim values in LDS
//   2) binary search on float bit patterns for the k-th smallest pairwise
//      difference (k = (m-1)//2, m = N(N-1)/2); count(diff <= x) via per-j
//      inner binary search (predicate monotone once sorted) + block reduce
//   median(squared diffs) = D*D where D is the k-th smallest |diff| (monotone)
// ---------------------------------------------------------------------------
__global__ void __launch_bounds__(512)
median_bw_kernel(const float* __restrict__ particles, float* __restrict__ inv_bw)
{
    const int d   = blockIdx.x;     // 0..127
    const int tid = threadIdx.x;    // 0..511

    __shared__ float v[NP];
    __shared__ int   cnt_s[8];
    __shared__ int   dec_s;

    v[tid] = particles[tid * DD + d];
    __syncthreads();

    // ---- bitonic sort ascending (n = 512) ----
    for (int k = 2; k <= NP; k <<= 1) {
        for (int s = k >> 1; s > 0; s >>= 1) {
            const int ixj = tid ^ s;
            if (ixj > tid) {
                const float a  = v[tid];
                const float b  = v[ixj];
                const bool  up = ((tid & k) == 0);
                if ((a > b) == up) { v[tid] = b; v[ixj] = a; }
            }
            __syncthreads();
        }
    }

    const float vj = v[tid];                       // this thread owns j = tid
    const int want1 = (NP * (NP - 1) / 2 - 1) / 2 + 1;  // 1-based rank 65408

    // ---- binary search on float bits of the diff value ----
    unsigned lo = 0u, hi = 0x7f800000u;
    while (lo < hi) {
        const unsigned mid = (lo + hi) >> 1;
        const float x = __uint_as_float(mid);

        // count i<j with fl(v[j]-v[i]) <= x ; predicate is monotone in i
        int loI = 0, hiI = tid;
        while (loI < hiI) {
            const int m = (loI + hiI) >> 1;
            if (vj - v[m] <= x) hiI = m; else loI = m + 1;
        }
        int cnt = tid - loI;

        // block reduce (wave shuffle then 8 partials)
        #pragma unroll
        for (int off = 32; off > 0; off >>= 1)
            cnt += __shfl_down(cnt, off);
        if ((tid & 63) == 0) cnt_s[tid >> 6] = cnt;
        __syncthreads();
        if (tid == 0) {
            int tot = 0;
            #pragma unroll
            for (int w = 0; w < 8; ++w) tot += cnt_s[w];
            dec_s = (tot >= want1) ? 1 : 0;
        }
        __syncthreads();
        if (dec_s) hi = mid; else lo = mid + 1;
        __syncthreads();   // protect cnt_s/dec_s before next iteration
    }

    if (tid == 0) {
        const float Dk     = __uint_as_float(lo); // k-th smallest |diff|
        const float median = Dk * Dk;             // k-th smallest squared diff
        const float h      = median / 6.240275844172107f;  // ln(513)
        const float bw     = fmaxf(h, 1e-9f);
        inv_bw[d] = 1.0f / bw;
    }
}

// ---------------------------------------------------------------------------
// Kernel 2: write log_kernel and grad_log_kernel, float4-vectorized.
// Flat float4 index t over (i, j, d4):  d4 = t & 31, j = (t>>5)&511, i = t>>14
// ---------------------------------------------------------------------------
__global__ void __launch_bounds__(256)
stein_out_kernel(const float* __restrict__ particles,
                 const float* __restrict__ inv_bw,
                 float4* __restrict__ out_lk,
                 float4* __restrict__ out_g)
{
    const float4* __restrict__ p4  = (const float4*)particles;
    const float4* __restrict__ ib4 = (const float4*)inv_bw;
    const int total = NP * NP * (DD / 4);   // 8,388,608

    for (int t = blockIdx.x * blockDim.x + threadIdx.x; t < total;
         t += gridDim.x * blockDim.x) {
        const int d4 = t & (DD / 4 - 1);        // 0..31
        const int j  = (t >> 5) & (NP - 1);     // 0..511
        const int i  = t >> 14;                 // 0..511

        const float4 xj = p4[j * (DD / 4) + d4];
        const float4 xi = p4[i * (DD / 4) + d4];
        const float4 ib = ib4[d4];

        float4 lk, g;
        {
            const float dx = xj.x - xi.x;
            lk.x = -(dx * dx * ib.x);
            g.x  = -2.0f * dx * ib.x;
        }
        {
            const float dx = xj.y - xi.y;
            lk.y = -(dx * dx * ib.y);
            g.y  = -2.0f * dx * ib.y;
        }
        {
            const float dx = xj.z - xi.z;
            lk.z = -(dx * dx * ib.z);
            g.z  = -2.0f * dx * ib.z;
        }
        {
            const float dx = xj.w - xi.w;
            lk.w = -(dx * dx * ib.w);
            g.w  = -2.0f * dx * ib.w;
        }
        out_lk[t] = lk;
        out_g[t]  = g;
    }
}

extern "C" void kernel_launch(void* const* d_in, const int* in_sizes, int n_in,
                              void* d_out, int out_size, void* d_ws, size_t ws_size,
                              hipStream_t stream)
{
    const float* particles = (const float*)d_in[0];
    float* out    = (float*)d_out;
    float* inv_bw = (float*)d_ws;   // 128 floats of scratch

    median_bw_kernel<<<DD, 512, 0, stream>>>(particles, inv_bw);

    float4* out_lk = (float4*)out;
    float4* out_g  = (float4*)(out + (size_t)NP * NP * DD);
    stein_out_kernel<<<2048, 256, 0, stream>>>(particles, inv_bw, out_lk, out_g);
}

// Round 3
// 72.271 us; speedup vs baseline: 4.1498x; 1.1548x over previous
//
#include <hip/hip_runtime.h>
#include <hip/hip_bf16.h>

#define NP 512   // particles
#define DD 128   // dims

// ---------------------------------------------------------------------------
// Kernel 1: per-dimension exact median of upper-triangular pairwise squared
// differences. One block (512 threads) per dimension d.
//   1) bitonic sort 512 values: register-resident, __shfl_xor for partner
//      distance < 64 (in-wave, no barrier), LDS exchange for s >= 64
//   2) bisection on float bit patterns for the k-th smallest pairwise diff
//      (k = (m-1)//2+1 1-based, m = N(N-1)/2). count(x) via per-j lower_bound
//      with WARM-STARTED brackets [A,B] (L(x) monotone in x), then a
//      1-barrier block reduce (double-buffered wave partials).
//   median(squared diffs) = Dk*Dk (x -> fl(x^2) monotone on non-neg floats)
// ---------------------------------------------------------------------------
__global__ void __launch_bounds__(512)
median_bw_kernel(const float* __restrict__ particles, float* __restrict__ inv_bw)
{
    const int d   = blockIdx.x;     // 0..127
    const int tid = threadIdx.x;    // 0..511

    __shared__ float v[NP];
    __shared__ int   cnt_s[2][8];

    float r = particles[tid * DD + d];

    // ---- hybrid bitonic sort ascending (n = 512) ----
    for (int k = 2; k <= NP; k <<= 1) {
        for (int s = k >> 1; s > 0; s >>= 1) {
            float other;
            if (s < 64) {
                other = __shfl_xor(r, s);       // in-wave, no barrier
            } else {
                __syncthreads();                // WAR: prior reads of v done
                v[tid] = r;
                __syncthreads();
                other = v[tid ^ s];
            }
            const bool lower = (tid & s) == 0;  // this thread is the low lane
            const bool up    = (tid & k) == 0;  // ascending sub-block
            r = (lower == up) ? fminf(r, other) : fmaxf(r, other);
        }
    }
    __syncthreads();          // WAR against last cross-stage reads
    v[tid] = r;
    __syncthreads();

    const float vj = r;       // sorted value owned by this thread (j = tid)
    const int want1 = (NP * (NP - 1) / 2 - 1) / 2 + 1;   // rank 65408 (1-based)

    const float maxd = v[NP - 1] - v[0];
    unsigned lo = 0u;
    unsigned hi = __float_as_uint(maxd) + 1u;  // answer in [lo, hi)

    // Per-thread bracket for L(x) = first i with fl(vj - v[i]) <= x.
    // L is non-increasing in x; bisection keeps L in [A, B].
    int A = 0, B = tid;       // B = tid is the "count 0" sentinel
    int buf = 0;

    while (lo < hi) {
        const unsigned mid = (lo + hi) >> 1;
        const float x = __uint_as_float(mid);

        int a = A, b = B;
        while (a < b) {
            const int m = (a + b) >> 1;
            if (vj - v[m] <= x) b = m; else a = m + 1;
        }
        int cnt = tid - a;    // #{i < j : fl(vj - v[i]) <= x}

        #pragma unroll
        for (int off = 32; off > 0; off >>= 1)
            cnt += __shfl_down(cnt, off);
        if ((tid & 63) == 0) cnt_s[buf][tid >> 6] = cnt;
        __syncthreads();

        int tot = 0;
        #pragma unroll
        for (int w = 0; w < 8; ++w) tot += cnt_s[buf][w];  // broadcast reads

        if (tot >= want1) { hi = mid;      A = a; }   // x shrinks -> L grows
        else             { lo = mid + 1u; B = a; }   // x grows  -> L shrinks
        buf ^= 1;
    }

    if (tid == 0) {
        const float Dk     = __uint_as_float(lo); // k-th smallest |diff|
        const float median = Dk * Dk;             // k-th smallest squared diff
        const float h      = median / 6.240275844172107f;  // ln(513), fp32
        const float bw     = fmaxf(h, 1e-9f);
        inv_bw[d] = 1.0f / bw;
    }
}

// ---------------------------------------------------------------------------
// Kernel 2: write log_kernel and grad_log_kernel, float4-vectorized.
// Flat float4 index t over (i, j, d4):  d4 = t & 31, j = (t>>5)&511, i = t>>14
// ---------------------------------------------------------------------------
__global__ void __launch_bounds__(256)
stein_out_kernel(const float* __restrict__ particles,
                 const float* __restrict__ inv_bw,
                 float4* __restrict__ out_lk,
                 float4* __restrict__ out_g)
{
    const float4* __restrict__ p4  = (const float4*)particles;
    const float4* __restrict__ ib4 = (const float4*)inv_bw;
    const int total = NP * NP * (DD / 4);   // 8,388,608

    for (int t = blockIdx.x * blockDim.x + threadIdx.x; t < total;
         t += gridDim.x * blockDim.x) {
        const int d4 = t & (DD / 4 - 1);        // 0..31
        const int j  = (t >> 5) & (NP - 1);     // 0..511
        const int i  = t >> 14;                 // 0..511

        const float4 xj = p4[j * (DD / 4) + d4];
        const float4 xi = p4[i * (DD / 4) + d4];
        const float4 ib = ib4[d4];

        float4 lk, g;
        {
            const float dx = xj.x - xi.x;
            lk.x = -(dx * dx * ib.x);
            g.x  = -2.0f * dx * ib.x;
        }
        {
            const float dx = xj.y - xi.y;
            lk.y = -(dx * dx * ib.y);
            g.y  = -2.0f * dx * ib.y;
        }
        {
            const float dx = xj.z - xi.z;
            lk.z = -(dx * dx * ib.z);
            g.z  = -2.0f * dx * ib.z;
        }
        {
            const float dx = xj.w - xi.w;
            lk.w = -(dx * dx * ib.w);
            g.w  = -2.0f * dx * ib.w;
        }
        out_lk[t] = lk;
        out_g[t]  = g;
    }
}

extern "C" void kernel_launch(void* const* d_in, const int* in_sizes, int n_in,
                              void* d_out, int out_size, void* d_ws, size_t ws_size,
                              hipStream_t stream)
{
    const float* particles = (const float*)d_in[0];
    float* out    = (float*)d_out;
    float* inv_bw = (float*)d_ws;   // 128 floats of scratch

    median_bw_kernel<<<DD, 512, 0, stream>>>(particles, inv_bw);

    float4* out_lk = (float4*)out;
    float4* out_g  = (float4*)(out + (size_t)NP * NP * DD);
    stein_out_kernel<<<2048, 256, 0, stream>>>(particles, inv_bw, out_lk, out_g);
}